// Round 1
// baseline (1003.141 us; speedup 1.0000x reference)
//
#include <hip/hip_runtime.h>

#define NEGF -1e10f

constexpr int N = 16, A = 5, Li = 32, Lqa = 64, D = 1024;
constexpr int NA = N * A;        // 80
constexpr int ROWS = NA * Li;    // 2560

// ---- block-wide sum over 256 threads (4 waves), broadcast to all ----
__device__ __forceinline__ float blk_sum256(float v, float* s4) {
#pragma unroll
  for (int o = 32; o > 0; o >>= 1) v += __shfl_down(v, o);
  if ((threadIdx.x & 63) == 0) s4[threadIdx.x >> 6] = v;
  __syncthreads();
  float r = s4[0] + s4[1] + s4[2] + s4[3];
  __syncthreads();
  return r;
}

// ---- 1) masked max-pool over Lqa: statement (ROWS, Lqa, D) -> ms (ROWS, D) ----
__global__ __launch_bounds__(256) void pool_kernel(const float* __restrict__ stmt,
                                                   const float* __restrict__ smask,
                                                   float* __restrict__ ms,
                                                   float* __restrict__ rmsk) {
  int blk = blockIdx.x;  // ((n*A+a)*Li+li)
  int t = threadIdx.x;
  const float* srow = stmt + (size_t)blk * Lqa * D;
  const float* mrow = smask + (size_t)blk * Lqa;
  __shared__ float mbuf[Lqa];
  if (t < Lqa) mbuf[t] = mrow[t];
  __syncthreads();
  float4 acc = make_float4(NEGF, NEGF, NEGF, NEGF);
  for (int q = 0; q < Lqa; ++q) {
    float m = mbuf[q];
    if (m != 0.f) {  // masked rows contribute exactly NEG == init; skip the load
      float w = (1.f - m) * NEGF;
      float4 v = *(const float4*)(srow + (size_t)q * D + t * 4);
      acc.x = fmaxf(acc.x, v.x * m + w);
      acc.y = fmaxf(acc.y, v.y * m + w);
      acc.z = fmaxf(acc.z, v.z * m + w);
      acc.w = fmaxf(acc.w, v.w * m + w);
    }
  }
  *(float4*)(ms + (size_t)blk * D + t * 4) = acc;
  if (t == 0) {
    float s = 0.f;
    for (int q = 0; q < Lqa; ++q) s += mbuf[q];
    rmsk[blk] = (s != 0.f) ? 1.f : 0.f;
  }
}

// ---- 2) row LayerNorm over D: y = LN(x)*g + b ----
__global__ __launch_bounds__(256) void ln_kernel(const float* __restrict__ x,
                                                 const float* __restrict__ g,
                                                 const float* __restrict__ b,
                                                 float* __restrict__ y) {
  __shared__ float s4[4];
  int r = blockIdx.x, t = threadIdx.x;
  const float* xr = x + (size_t)r * D;
  float4 v = *(const float4*)(xr + t * 4);
  float sum = blk_sum256(v.x + v.y + v.z + v.w, s4);
  float mu = sum * (1.f / D);
  float4 d = make_float4(v.x - mu, v.y - mu, v.z - mu, v.w - mu);
  float sq = blk_sum256(d.x * d.x + d.y * d.y + d.z * d.z + d.w * d.w, s4);
  float rs = rsqrtf(sq * (1.f / D) + 1e-5f);
  float4 g4 = *(const float4*)(g + t * 4);
  float4 b4 = *(const float4*)(b + t * 4);
  float4 o;
  o.x = d.x * rs * g4.x + b4.x;
  o.y = d.y * rs * g4.y + b4.y;
  o.z = d.z * rs * g4.z + b4.z;
  o.w = d.w * rs * g4.w + b4.w;
  *(float4*)(y + (size_t)r * D + t * 4) = o;
}

// ---- 3) fp32 GEMM 2560x1024x1024 + bias + relu + residual ----
// Xout = Xin + relu(Y @ W + bias); 64x64 tile, K-step 16, 4x4 per thread
__global__ __launch_bounds__(256) void gemm_kernel(const float* __restrict__ Yl,
                                                   const float* __restrict__ W,
                                                   const float* __restrict__ bias,
                                                   const float* __restrict__ Xin,
                                                   float* __restrict__ Xout) {
  __shared__ float As[16][64];
  __shared__ float Bs[16][64];
  int t = threadIdx.x;
  int tx = t & 15, ty = t >> 4;
  int bm = blockIdx.y * 64, bn = blockIdx.x * 64;
  int lm = t >> 2;           // A-load row 0..63
  int lk = (t & 3) * 4;      // A-load k offset
  int bk = t >> 4;           // B-load k 0..15
  int bnoff = (t & 15) * 4;  // B-load col offset
  float acc[4][4] = {};
  for (int k0 = 0; k0 < D; k0 += 16) {
    float4 a4 = *(const float4*)(Yl + (size_t)(bm + lm) * D + k0 + lk);
    float4 b4 = *(const float4*)(W + (size_t)(k0 + bk) * D + bn + bnoff);
    As[lk + 0][lm] = a4.x;
    As[lk + 1][lm] = a4.y;
    As[lk + 2][lm] = a4.z;
    As[lk + 3][lm] = a4.w;
    *(float4*)&Bs[bk][bnoff] = b4;
    __syncthreads();
#pragma unroll
    for (int k = 0; k < 16; ++k) {
      float a0 = As[k][ty * 4 + 0];
      float a1 = As[k][ty * 4 + 1];
      float a2 = As[k][ty * 4 + 2];
      float a3 = As[k][ty * 4 + 3];
      float4 bb = *(float4*)&Bs[k][tx * 4];
      acc[0][0] += a0 * bb.x; acc[0][1] += a0 * bb.y; acc[0][2] += a0 * bb.z; acc[0][3] += a0 * bb.w;
      acc[1][0] += a1 * bb.x; acc[1][1] += a1 * bb.y; acc[1][2] += a1 * bb.z; acc[1][3] += a1 * bb.w;
      acc[2][0] += a2 * bb.x; acc[2][1] += a2 * bb.y; acc[2][2] += a2 * bb.z; acc[2][3] += a2 * bb.w;
      acc[3][0] += a3 * bb.x; acc[3][1] += a3 * bb.y; acc[3][2] += a3 * bb.z; acc[3][3] += a3 * bb.w;
    }
    __syncthreads();
  }
  float4 bias4 = *(const float4*)(bias + bn + tx * 4);
#pragma unroll
  for (int i = 0; i < 4; ++i) {
    int row = bm + ty * 4 + i;
    float4 xv = *(const float4*)(Xin + (size_t)row * D + bn + tx * 4);
    float4 o;
    o.x = xv.x + fmaxf(acc[i][0] + bias4.x, 0.f);
    o.y = xv.y + fmaxf(acc[i][1] + bias4.y, 0.f);
    o.z = xv.z + fmaxf(acc[i][2] + bias4.z, 0.f);
    o.w = xv.w + fmaxf(acc[i][3] + bias4.w, 0.f);
    *(float4*)(Xout + (size_t)row * D + bn + tx * 4) = o;
  }
}

// ---- 4) heads: t_st/t_ed = LN(x)*{g,b} @ w + bias, mask -> temporal (d_out+96) ----
__global__ __launch_bounds__(256) void heads_kernel(
    const float* __restrict__ X,
    const float* __restrict__ st_g, const float* __restrict__ st_b,
    const float* __restrict__ st_w, const float* __restrict__ st_bias,
    const float* __restrict__ ed_g, const float* __restrict__ ed_b,
    const float* __restrict__ ed_w, const float* __restrict__ ed_bias,
    const float* __restrict__ tsm, float* __restrict__ out_temporal) {
  __shared__ float s4[4];
  int r = blockIdx.x, t = threadIdx.x;
  const float* xr = X + (size_t)r * D;
  float4 v = *(const float4*)(xr + t * 4);
  float sum = blk_sum256(v.x + v.y + v.z + v.w, s4);
  float mu = sum * (1.f / D);
  float4 d = make_float4(v.x - mu, v.y - mu, v.z - mu, v.w - mu);
  float sq = blk_sum256(d.x * d.x + d.y * d.y + d.z * d.z + d.w * d.w, s4);
  float rs = rsqrtf(sq * (1.f / D) + 1e-5f);
  float4 sg = *(const float4*)(st_g + t * 4), sb = *(const float4*)(st_b + t * 4);
  float4 eg = *(const float4*)(ed_g + t * 4), eb = *(const float4*)(ed_b + t * 4);
  float4 ws = *(const float4*)(st_w + t * 4), we = *(const float4*)(ed_w + t * 4);
  float dst = (d.x * rs * sg.x + sb.x) * ws.x + (d.y * rs * sg.y + sb.y) * ws.y +
              (d.z * rs * sg.z + sb.z) * ws.z + (d.w * rs * sg.w + sb.w) * ws.w;
  float ded = (d.x * rs * eg.x + eb.x) * we.x + (d.y * rs * eg.y + eb.y) * we.y +
              (d.z * rs * eg.z + eb.z) * we.z + (d.w * rs * eg.w + eb.w) * we.w;
  dst = blk_sum256(dst, s4);
  ded = blk_sum256(ded, s4);
  if (t == 0) {
    int li = r & (Li - 1);
    int n = r / (A * Li);
    float m = tsm[n * Li + li];
    float im = (1.f - m) * NEGF;
    out_temporal[r * 2 + 0] = (dst + st_bias[0]) * m + im;
    out_temporal[r * 2 + 1] = (ded + ed_bias[0]) * m + im;
  }
}

// ---- 5) per-(n,a): softmax over Li, top-1 span, loc/glob max-pool, cls LN+dot ----
__global__ __launch_bounds__(256) void cls_kernel(
    const float* __restrict__ X, const float* __restrict__ rmsk,
    const float* __restrict__ temporal,
    const float* __restrict__ cls_g, const float* __restrict__ cls_b,
    const float* __restrict__ cls_w, const float* __restrict__ cls_bias,
    const int* __restrict__ targets, float* __restrict__ out) {
  int na = blockIdx.x, t = threadIdx.x;
  __shared__ float p_st[Li], p_ed[Li];
  __shared__ float tb[2 * Li];
  __shared__ float s4[4];
  __shared__ float sv[256];
  __shared__ int si[256];
  if (t < 2 * Li) tb[t] = temporal[na * 2 * Li + t];
  __syncthreads();
  if (t < 64) {  // wave 0: lanes 0..31 -> st channel, 32..63 -> ed channel
    int ch = t >> 5, li = t & 31;
    float v = tb[li * 2 + ch];
    float m = v;
#pragma unroll
    for (int o = 16; o > 0; o >>= 1) m = fmaxf(m, __shfl_xor(m, o));
    float e = expf(v - m);
    float s = e;
#pragma unroll
    for (int o = 16; o > 0; o >>= 1) s += __shfl_xor(s, o);
    float p = e / s;
    if (ch == 0) p_st[li] = p; else p_ed[li] = p;
  }
  __syncthreads();
  // argmax over sc[st][ed] = p_st*p_ed (upper tri incl diag), first-index tiebreak
  float best = -2.f;
  int bidx = 1 << 30;
  for (int i = t; i < Li * Li; i += 256) {
    int stq = i >> 5, edq = i & 31;
    float v = (stq <= edq) ? p_st[stq] * p_ed[edq] : -1.f;
    if (v > best) { best = v; bidx = i; }  // ascending i => lowest idx kept on ties
  }
  sv[t] = best; si[t] = bidx;
  __syncthreads();
  for (int o = 128; o > 0; o >>= 1) {
    if (t < o) {
      float v2 = sv[t + o]; int i2 = si[t + o];
      if (v2 > sv[t] || (v2 == sv[t] && i2 < si[t])) { sv[t] = v2; si[t] = i2; }
    }
    __syncthreads();
  }
  int idx = si[0];
  int stq = idx >> 5, edq = idx & 31;
  int st2 = stq - 3; if (st2 < 0) st2 = 0;
  int ed2 = edq + 4;  // exclusive
  const float* xb = X + (size_t)na * Li * D;
  float4 loc = make_float4(NEGF, NEGF, NEGF, NEGF);
  float4 glob = loc;
  for (int li = 0; li < Li; ++li) {
    float m = rmsk[na * Li + li];
    float cm = (li >= st2 && li < ed2) ? m : 0.f;
    float im = (1.f - m) * NEGF, icm = (1.f - cm) * NEGF;
    float4 v = *(const float4*)(xb + (size_t)li * D + t * 4);
    glob.x = fmaxf(glob.x, v.x * m + im);
    glob.y = fmaxf(glob.y, v.y * m + im);
    glob.z = fmaxf(glob.z, v.z * m + im);
    glob.w = fmaxf(glob.w, v.w * m + im);
    loc.x = fmaxf(loc.x, v.x * cm + icm);
    loc.y = fmaxf(loc.y, v.y * cm + icm);
    loc.z = fmaxf(loc.z, v.z * cm + icm);
    loc.w = fmaxf(loc.w, v.w * cm + icm);
  }
  // LN over 2048 of mm = [loc(0..1023), glob(1024..2047)], then dot cls_w
  float sum = loc.x + loc.y + loc.z + loc.w + glob.x + glob.y + glob.z + glob.w;
  sum = blk_sum256(sum, s4);
  float mu = sum * (1.f / (2 * D));
  float dl[4] = {loc.x - mu, loc.y - mu, loc.z - mu, loc.w - mu};
  float dg[4] = {glob.x - mu, glob.y - mu, glob.z - mu, glob.w - mu};
  float sq = dl[0]*dl[0] + dl[1]*dl[1] + dl[2]*dl[2] + dl[3]*dl[3] +
             dg[0]*dg[0] + dg[1]*dg[1] + dg[2]*dg[2] + dg[3]*dg[3];
  sq = blk_sum256(sq, s4);
  float rs = rsqrtf(sq * (1.f / (2 * D)) + 1e-5f);
  int dlo = t * 4, dgo = D + t * 4;
  float4 gl = *(const float4*)(cls_g + dlo), bl = *(const float4*)(cls_b + dlo);
  float4 wl = *(const float4*)(cls_w + dlo);
  float4 gg = *(const float4*)(cls_g + dgo), bg = *(const float4*)(cls_b + dgo);
  float4 wg = *(const float4*)(cls_w + dgo);
  float dot = (dl[0] * rs * gl.x + bl.x) * wl.x + (dl[1] * rs * gl.y + bl.y) * wl.y +
              (dl[2] * rs * gl.z + bl.z) * wl.z + (dl[3] * rs * gl.w + bl.w) * wl.w +
              (dg[0] * rs * gg.x + bg.x) * wg.x + (dg[1] * rs * gg.y + bg.y) * wg.y +
              (dg[2] * rs * gg.z + bg.z) * wg.z + (dg[3] * rs * gg.w + bg.w) * wg.w;
  dot = blk_sum256(dot, s4);
  if (t == 0) {
    out[na] = dot + cls_bias[0];
    if (na < N) out[NA + na] = (float)targets[na];  // targets as float
  }
}

extern "C" void kernel_launch(void* const* d_in, const int* in_sizes, int n_in,
                              void* d_out, int out_size, void* d_ws, size_t ws_size,
                              hipStream_t stream) {
  const float* statement = (const float*)d_in[0];
  const float* smask     = (const float*)d_in[1];
  const int*   targets   = (const int*)d_in[2];
  // d_in[3] ts_labels: unused in eval path
  const float* tsm       = (const float*)d_in[4];
  const float* proj_g    = (const float*)d_in[5];
  const float* proj_b    = (const float*)d_in[6];
  const float* proj_w    = (const float*)d_in[7];
  const float* proj_bias = (const float*)d_in[8];
  const float* st_g      = (const float*)d_in[9];
  const float* st_b      = (const float*)d_in[10];
  const float* st_w      = (const float*)d_in[11];
  const float* st_bias   = (const float*)d_in[12];
  const float* ed_g      = (const float*)d_in[13];
  const float* ed_b      = (const float*)d_in[14];
  const float* ed_w      = (const float*)d_in[15];
  const float* ed_bias   = (const float*)d_in[16];
  const float* cls_g     = (const float*)d_in[17];
  const float* cls_b     = (const float*)d_in[18];
  const float* cls_w     = (const float*)d_in[19];
  const float* cls_bias  = (const float*)d_in[20];

  float* ws = (float*)d_ws;
  float* ms   = ws;                        // ROWS*D  (max_statement)
  float* yln  = ws + (size_t)ROWS * D;     // ROWS*D  (LN(ms))
  float* xo   = ws + (size_t)2 * ROWS * D; // ROWS*D  (x after residual proj)
  float* rmsk = ws + (size_t)3 * ROWS * D; // ROWS    (ms_mask)

  float* out = (float*)d_out;
  float* out_temporal = out + NA + N;      // [96 : 96+5120]

  pool_kernel<<<ROWS, 256, 0, stream>>>(statement, smask, ms, rmsk);
  ln_kernel<<<ROWS, 256, 0, stream>>>(ms, proj_g, proj_b, yln);
  dim3 gg(D / 64, ROWS / 64);
  gemm_kernel<<<gg, 256, 0, stream>>>(yln, proj_w, proj_bias, ms, xo);
  heads_kernel<<<ROWS, 256, 0, stream>>>(xo, st_g, st_b, st_w, st_bias,
                                         ed_g, ed_b, ed_w, ed_bias, tsm, out_temporal);
  cls_kernel<<<NA, 256, 0, stream>>>(xo, rmsk, out_temporal,
                                     cls_g, cls_b, cls_w, cls_bias, targets, out);
}